// Round 12
// baseline (107.903 us; speedup 1.0000x reference)
//
#include <hip/hip_runtime.h>
#include <hip/hip_bf16.h>

// Problem: GraphAttentionLayer  B=16, L=128, DIN=768, DH=300, DE=100
// Device dtypes: all float tensors fp32, adj int32, out fp32.
//
// R11->R12 DIAGNOSTIC: probes proved EE streams at 6.3 TB/s (16.6us) and
// kernel costs add linearly. All k_ef restructures null => attribution
// unknown. This round: k_ef body x4 and k_sm_pv body x3 IN-KERNEL
// (idempotent, asm memory barrier per rep defeats CSE) so both exceed the
// ~60us harness-fill flood and appear in top-5 WITH their counters.
// Wall = base(72.5) + 3*ef + 2*smpv cross-checks.

#define L 128
#define DH 300
#define DIN 768
#define DE 100
#define SPLITK 4
#define MROWS 2048
#define IG 2
#define SL ((size_t)MROWS * DH)

typedef __bf16 bf16x8 __attribute__((ext_vector_type(8)));
typedef float f32x4 __attribute__((ext_vector_type(4)));
typedef unsigned short ushort_t;

__device__ __forceinline__ ushort_t f2bf(float f) {
    __bf16 h = (__bf16)f;
    ushort_t u;
    __builtin_memcpy(&u, &h, 2);
    return u;
}

// ---------------- k_small ----------------
__global__ __launch_bounds__(256) void k_small(
    const float* __restrict__ A, const float* __restrict__ EMW,
    const float* __restrict__ EMB, const float* __restrict__ ELW,
    const float* __restrict__ ELB,
    float* __restrict__ CV, float* __restrict__ C0,
    float* __restrict__ VW, int* __restrict__ VCOL)
{
    int t = threadIdx.x;
    if (blockIdx.x == 0) {
        if (t < DE) {
            float s0 = 0.f, s1 = 0.f, s2 = 0.f, s3 = 0.f, s4 = 0.f, s5 = 0.f;
            for (int k = 0; k < DH; k += 6) {
                s0 = fmaf(ELW[k + 0], EMW[(k + 0) * DE + t], s0);
                s1 = fmaf(ELW[k + 1], EMW[(k + 1) * DE + t], s1);
                s2 = fmaf(ELW[k + 2], EMW[(k + 2) * DE + t], s2);
                s3 = fmaf(ELW[k + 3], EMW[(k + 3) * DE + t], s3);
                s4 = fmaf(ELW[k + 4], EMW[(k + 4) * DE + t], s4);
                s5 = fmaf(ELW[k + 5], EMW[(k + 5) * DE + t], s5);
            }
            CV[t] = ((s0 + s1) + (s2 + s3)) + (s4 + s5);
        } else if (t == DE) {
            float s0 = 0.f;
            for (int k = 0; k < DH; ++k) s0 = fmaf(ELW[k], EMB[k], s0);
            C0[0] = s0 + ELB[0];
        }
    } else {
        if (t < L) {
            int base = t * DH;
            int cm = base >> 7;
            float w0 = 0.f, w1 = 0.f, w2 = 0.f, w3 = 0.f;
            for (int j = 0; j < DH; ++j) {
                int u = ((base + j) >> 7) - cm;
                float av = A[j];
                w0 += (u == 0) ? av : 0.f;
                w1 += (u == 1) ? av : 0.f;
                w2 += (u == 2) ? av : 0.f;
                w3 += (u == 3) ? av : 0.f;
            }
            VCOL[t] = cm;
            VW[t * 4 + 0] = w0; VW[t * 4 + 1] = w1;
            VW[t * 4 + 2] = w2; VW[t * 4 + 3] = w3;
        }
    }
}

// ---------------- k_cvt ----------------
__global__ __launch_bounds__(256) void k_cvt(
    const float* __restrict__ Wm, ushort_t* __restrict__ WT)
{
    __shared__ float tile[64][65];
    int k0 = blockIdx.x * 64;
    int c0 = blockIdx.y * 64;
    int t = threadIdx.x;
#pragma unroll
    for (int s = 0; s < 16; ++s) {
        int idx = t + 256 * s;
        int kr = idx >> 6, cc = idx & 63;
        int c = c0 + cc;
        tile[kr][cc] = (c < DH) ? Wm[(size_t)(k0 + kr) * DH + c] : 0.f;
    }
    __syncthreads();
#pragma unroll
    for (int s = 0; s < 16; ++s) {
        int idx = t + 256 * s;
        int c = idx >> 6, kr = idx & 63;
        WT[(size_t)(c0 + c) * DIN + k0 + kr] = f2bf(tile[kr][c]);
    }
}

// ---------------- k_gemm (MFMA bf16) ----------------
__global__ __launch_bounds__(256) void k_gemm(
    const float* __restrict__ X, const ushort_t* __restrict__ WT,
    float* __restrict__ HP)
{
    __shared__ ushort_t As[64 * 72];
    __shared__ ushort_t Bs[64 * 72];
    int t = threadIdx.x;
    int w = t >> 6;
    int lane = t & 63;
    int lr = lane & 15;
    int lk = lane >> 4;
    int r0 = blockIdx.y * 64;
    int c0 = blockIdx.x * 64;
    int kbase = blockIdx.z * (DIN / SPLITK);

    f32x4 acc[4];
#pragma unroll
    for (int ct = 0; ct < 4; ++ct) acc[ct] = (f32x4){0.f, 0.f, 0.f, 0.f};

    int srow = t >> 2, skq = (t & 3) * 16;

    for (int step = 0; step < 3; ++step) {
        int kk = kbase + step * 64;
        {
            const float4* xs = (const float4*)(X + (size_t)(r0 + srow) * DIN + kk + skq);
            float4 f0 = xs[0], f1 = xs[1], f2 = xs[2], f3 = xs[3];
            bf16x8 v0, v1;
            v0[0] = (__bf16)f0.x; v0[1] = (__bf16)f0.y; v0[2] = (__bf16)f0.z; v0[3] = (__bf16)f0.w;
            v0[4] = (__bf16)f1.x; v0[5] = (__bf16)f1.y; v0[6] = (__bf16)f1.z; v0[7] = (__bf16)f1.w;
            v1[0] = (__bf16)f2.x; v1[1] = (__bf16)f2.y; v1[2] = (__bf16)f2.z; v1[3] = (__bf16)f2.w;
            v1[4] = (__bf16)f3.x; v1[5] = (__bf16)f3.y; v1[6] = (__bf16)f3.z; v1[7] = (__bf16)f3.w;
            *(bf16x8*)&As[srow * 72 + skq] = v0;
            *(bf16x8*)&As[srow * 72 + skq + 8] = v1;
        }
        {
            const uint4* wp = (const uint4*)(WT + (size_t)(c0 + srow) * DIN + kk + skq);
            uint4 u0 = wp[0], u1 = wp[1];
            *(uint4*)&Bs[srow * 72 + skq] = u0;
            *(uint4*)&Bs[srow * 72 + skq + 8] = u1;
        }
        __syncthreads();
#pragma unroll
        for (int k2 = 0; k2 < 2; ++k2) {
            bf16x8 af = *(bf16x8*)&As[(w * 16 + lr) * 72 + k2 * 32 + lk * 8];
#pragma unroll
            for (int ct = 0; ct < 4; ++ct) {
                bf16x8 bf_ = *(bf16x8*)&Bs[(ct * 16 + lr) * 72 + k2 * 32 + lk * 8];
                acc[ct] = __builtin_amdgcn_mfma_f32_16x16x32_bf16(af, bf_, acc[ct], 0, 0, 0);
            }
        }
        __syncthreads();
    }
    float* outp = HP + (size_t)blockIdx.z * SL;
#pragma unroll
    for (int ct = 0; ct < 4; ++ct) {
        int col = c0 + ct * 16 + lr;
        if (col < DH) {
#pragma unroll
            for (int r = 0; r < 4; ++r) {
                int row = r0 + w * 16 + lk * 4 + r;
                outp[(size_t)row * DH + col] = acc[ct][r];
            }
        }
    }
}

// ---------------- k_red ----------------
__global__ __launch_bounds__(256) void k_red(
    const float* __restrict__ HP, const float* __restrict__ A,
    float* __restrict__ H, float* __restrict__ E2)
{
    int t = threadIdx.x;
    int row = blockIdx.x * 8 + (t >> 5);
    int lane = t & 31;
    const float4* a4 = (const float4*)(A + DH);
    float4* hout = (float4*)(H + (size_t)row * DH);
    float acc = 0.f;
    for (int k4 = lane; k4 < DH / 4; k4 += 32) {
        float4 hv; hv.x = 0.f; hv.y = 0.f; hv.z = 0.f; hv.w = 0.f;
#pragma unroll
        for (int z = 0; z < SPLITK; ++z) {
            float4 v = ((const float4*)(HP + (size_t)z * SL + (size_t)row * DH))[k4];
            hv.x += v.x; hv.y += v.y; hv.z += v.z; hv.w += v.w;
        }
        float4 av = a4[k4];
        hout[k4] = hv;
        acc += hv.x * av.x + hv.y * av.y + hv.z * av.z + hv.w * av.w;
    }
#pragma unroll
    for (int o = 16; o >= 1; o >>= 1) acc += __shfl_xor(acc, o);
    if (lane == 0) E2[row] = acc;
}

// ---------------- k_ef: R9 structure, body x4 (DIAGNOSTIC repeat) ----------------
__global__ __launch_bounds__(256) void k_ef(
    const float* __restrict__ EE, const float* __restrict__ CV,
    const float* __restrict__ C0, float* __restrict__ S)
{
    __shared__ __align__(16) float cl[DE];
    __shared__ float ps[3200];
    int bid = blockIdx.x;
    int t = threadIdx.x;
    if (t < DE) cl[t] = CV[t];
    const float c0v = C0[0];
    const f32x4* src = (const f32x4*)(EE + (size_t)bid * (L * DE));

    for (int rep = 0; rep < 4; ++rep) {
        asm volatile("" ::: "memory");     // defeat cross-rep CSE/hoist
        __syncthreads();                   // ps reuse (rep0: cl ready)

        f32x4 v[13];
#pragma unroll
        for (int s = 0; s < 12; ++s) v[s] = src[t + 256 * s];
        if (t < 128) v[12] = src[t + 3072];
        else { v[12][0] = 0.f; v[12][1] = 0.f; v[12][2] = 0.f; v[12][3] = 0.f; }

        int p = t % 25;
#pragma unroll
        for (int s = 0; s < 13; ++s) {
            int idx = t + 256 * s;
            if (s < 12 || t < 128) {
                const float4 c4 = *(const float4*)&cl[p * 4];
                ps[idx] = v[s][0] * c4.x + v[s][1] * c4.y + v[s][2] * c4.z + v[s][3] * c4.w;
            }
            p += 6; if (p >= 25) p -= 25;
        }
        __syncthreads();

        int r = t >> 1, h = t & 1;
        const float* pp = ps + 25 * r + h * 13;
        float s0 = 0.f;
#pragma unroll
        for (int m = 0; m < 12; ++m) s0 += pp[m];
        if (h == 0) s0 += pp[12];
        s0 += __shfl_xor(s0, 1);
        if (h == 0) S[(size_t)bid * L + r] = s0 + c0v;
    }
}

// ---------------- k_sm_pv: body x3 (DIAGNOSTIC repeat) ----------------
__global__ __launch_bounds__(256) void k_sm_pv(
    const float* __restrict__ S, const int* __restrict__ ADJ,
    const float* __restrict__ H, const float* __restrict__ E2,
    const float* __restrict__ VW, const int* __restrict__ VCOL,
    float* __restrict__ OUT)
{
    __shared__ float hrow[IG][DH];
    __shared__ float att[IG][L];
    int blk = blockIdx.x;
    int b = blk >> 6;
    int i0 = (blk & 63) * IG;
    int bid0 = b * L + i0;
    int t = threadIdx.x;

    for (int rep = 0; rep < 3; ++rep) {
        asm volatile("" ::: "memory");     // defeat cross-rep CSE/hoist
        __syncthreads();                   // att/hrow reuse across reps

        for (int idx = t; idx < IG * DH; idx += 256) {
            int r = idx / DH, k = idx - r * DH;
            hrow[r][k] = H[(size_t)(bid0 + r) * DH + k];
        }
        __syncthreads();

        {
            int r = t >> 7, j = t & 127;
            int bid = bid0 + r;
            float s = S[(size_t)bid * L + j];
            float ewv = 1.f / (1.f + expf(-s));
            int cm = VCOL[j];
            float e1 = 0.f;
#pragma unroll
            for (int u = 0; u < 4; ++u) {
                int c = cm + u; if (c > DH - 1) c = DH - 1;
                e1 += VW[j * 4 + u] * hrow[r][c];
            }
            float e = e1 + E2[(size_t)b * L + j];
            e = (e > 0.f) ? e : 0.2f * e;
            att[r][j] = (ADJ[(size_t)bid * L + j] > 0) ? e * ewv : -9.0e15f;
        }
        __syncthreads();

        {
            int w = t >> 6, lane = t & 63;
            if (w < IG) {
                float v0 = att[w][lane], v1 = att[w][lane + 64];
                float m = fmaxf(v0, v1);
#pragma unroll
                for (int o = 32; o >= 1; o >>= 1) m = fmaxf(m, __shfl_xor(m, o));
                float p0 = expf(v0 - m), p1 = expf(v1 - m);
                float sm = p0 + p1;
#pragma unroll
                for (int o = 32; o >= 1; o >>= 1) sm += __shfl_xor(sm, o);
                float inv = 1.f / sm;
                att[w][lane] = p0 * inv;
                att[w][lane + 64] = p1 * inv;
            }
        }
        __syncthreads();

        const float* Hb = H + (size_t)b * L * DH;
        for (int k = t; k < DH; k += 256) {
            float a0 = hrow[0][k], c0a = 0.f;
            float a1 = hrow[1][k], c1a = 0.f;
#pragma unroll 2
            for (int j = 0; j < L; j += 4) {
                float h0 = Hb[(size_t)(j + 0) * DH + k];
                float h1 = Hb[(size_t)(j + 1) * DH + k];
                float h2 = Hb[(size_t)(j + 2) * DH + k];
                float h3 = Hb[(size_t)(j + 3) * DH + k];
                a0  = fmaf(att[0][j + 0], h0, a0);
                c0a = fmaf(att[0][j + 1], h1, c0a);
                a0  = fmaf(att[0][j + 2], h2, a0);
                c0a = fmaf(att[0][j + 3], h3, c0a);
                a1  = fmaf(att[1][j + 0], h0, a1);
                c1a = fmaf(att[1][j + 1], h1, c1a);
                a1  = fmaf(att[1][j + 2], h2, a1);
                c1a = fmaf(att[1][j + 3], h3, c1a);
            }
            OUT[(size_t)(bid0 + 0) * DH + k] = a0 + c0a;
            OUT[(size_t)(bid0 + 1) * DH + k] = a1 + c1a;
        }
    }
}

extern "C" void kernel_launch(void* const* d_in, const int* in_sizes, int n_in,
                              void* d_out, int out_size, void* d_ws, size_t ws_size,
                              hipStream_t stream) {
    const float* X   = (const float*)d_in[0];
    const int*   ADJ = (const int*)d_in[1];
    const float* EE  = (const float*)d_in[2];
    const float* Wm  = (const float*)d_in[3];
    const float* A   = (const float*)d_in[4];
    const float* EMW = (const float*)d_in[5];
    const float* EMB = (const float*)d_in[6];
    const float* ELW = (const float*)d_in[7];
    const float* ELB = (const float*)d_in[8];
    float* OUT = (float*)d_out;

    float* ws = (float*)d_ws;
    float* HP   = ws;                    // 4 * 614400 = 2457600
    float* H    = ws + 2457600;          // 614400
    float* E2   = ws + 3072000;          // 2048
    float* CV   = ws + 3074048;          // 100
    float* C0   = ws + 3074148;          // 4 (pad)
    float* VW   = ws + 3074152;          // 512
    int*   VCOL = (int*)(ws + 3074664);  // 128 (+pad 24)
    ushort_t* WT = (ushort_t*)(ws + 3074816); // 320*768 bf16
    float* Sbuf = ws + 3197696;          // 2048*128

    k_small<<<dim3(2), dim3(256), 0, stream>>>(A, EMW, EMB, ELW, ELB, CV, C0, VW, VCOL);
    k_cvt<<<dim3(12, 5), dim3(256), 0, stream>>>(Wm, WT);
    k_gemm<<<dim3(5, 32, SPLITK), dim3(256), 0, stream>>>(X, WT, HP);
    k_red<<<dim3(256), dim3(256), 0, stream>>>(HP, A, H, E2);
    k_ef<<<dim3(2048), dim3(256), 0, stream>>>(EE, CV, C0, Sbuf);
    k_sm_pv<<<dim3(1024), dim3(256), 0, stream>>>(Sbuf, ADJ, H, E2, VW, VCOL, OUT);
}

// Round 13
// 79.710 us; speedup vs baseline: 1.3537x; 1.3537x over previous
//
#include <hip/hip_runtime.h>
#include <hip/hip_bf16.h>

// Problem: GraphAttentionLayer  B=16, L=128, DIN=768, DH=300, DE=100
// Device dtypes: all float tensors fp32, adj int32, out fp32.
//
// R12->R13: repeat-diagnostic gave ef(warm)~10us, smpv~3us => attention path
// is FAST; ~50us hides in {small,cvt,gemm,red}+overhead (never measured).
// This round: (1) k_pre fuses small+cvt with closed-form band-V (LDS A) and
// parallel CV/C0 (suspect fix); (2) gemm x3 and red x3 in-kernel so either
// appears in top-5 with counters if >=20us (diagnostic).

#define L 128
#define DH 300
#define DIN 768
#define DE 100
#define SPLITK 4
#define MROWS 2048
#define IG 2
#define SL ((size_t)MROWS * DH)

typedef __bf16 bf16x8 __attribute__((ext_vector_type(8)));
typedef float f32x4 __attribute__((ext_vector_type(4)));
typedef unsigned short ushort_t;

__device__ __forceinline__ ushort_t f2bf(float f) {
    __bf16 h = (__bf16)f;
    ushort_t u;
    __builtin_memcpy(&u, &h, 2);
    return u;
}

// ---------------- k_pre: fused small + cvt ----------------
// block 0: CV (2 threads/d, shfl pair-reduce) + C0 (wave 0 reduce)
// block 1: band-sparse V via LDS-staged A + closed-form segments
// blocks 2..61: W -> WT bf16 transpose tiles
__global__ __launch_bounds__(256) void k_pre(
    const float* __restrict__ A, const float* __restrict__ EMW,
    const float* __restrict__ EMB, const float* __restrict__ ELW,
    const float* __restrict__ ELB, const float* __restrict__ Wm,
    float* __restrict__ CV, float* __restrict__ C0,
    float* __restrict__ VW, int* __restrict__ VCOL,
    ushort_t* __restrict__ WT)
{
    __shared__ float tile[64][65];
    __shared__ float Als[304];
    int t = threadIdx.x;
    int blk = blockIdx.x;

    if (blk == 0) {
        // CV: d = t>>1 (d<100), g = t&1 handles k = g*150..+150
        float part = 0.f;
        int d = t >> 1, g = t & 1;
        if (d < DE) {
            int k0 = g * 150;
            for (int k = k0; k < k0 + 150; ++k)
                part = fmaf(ELW[k], EMW[k * DE + d], part);
        }
        part += __shfl_xor(part, 1);
        if (d < DE && g == 0) CV[d] = part;
        // C0: wave 0 (t<64): k = t + 64*i
        if (t < 64) {
            float s = 0.f;
            for (int k = t; k < DH; k += 64) s = fmaf(ELW[k], EMB[k], s);
#pragma unroll
            for (int o = 32; o >= 1; o >>= 1) s += __shfl_xor(s, o);
            if (t == 0) C0[0] = s + ELB[0];
        }
    } else if (blk == 1) {
        for (int idx = t; idx < DH; idx += 256) Als[idx] = A[idx];
        __syncthreads();
        if (t < L) {
            int base = t * DH;
            int cm = base >> 7;
            float w[4];
#pragma unroll
            for (int u = 0; u < 4; ++u) {
                int js = 128 * (cm + u) - base;
                int je = js + 128;
                if (js < 0) js = 0;
                if (je > DH) je = DH;
                float s = 0.f;
                for (int j = js; j < je; ++j) s += Als[j];
                w[u] = (je > js) ? s : 0.f;
            }
            VCOL[t] = cm;
            VW[t * 4 + 0] = w[0]; VW[t * 4 + 1] = w[1];
            VW[t * 4 + 2] = w[2]; VW[t * 4 + 3] = w[3];
        }
    } else {
        int blk2 = blk - 2;
        int k0 = (blk2 % 12) * 64;
        int c0 = (blk2 / 12) * 64;
#pragma unroll
        for (int s = 0; s < 16; ++s) {
            int idx = t + 256 * s;
            int kr = idx >> 6, cc = idx & 63;
            int c = c0 + cc;
            tile[kr][cc] = (c < DH) ? Wm[(size_t)(k0 + kr) * DH + c] : 0.f;
        }
        __syncthreads();
#pragma unroll
        for (int s = 0; s < 16; ++s) {
            int idx = t + 256 * s;
            int c = idx >> 6, kr = idx & 63;
            WT[(size_t)(c0 + c) * DIN + k0 + kr] = f2bf(tile[kr][c]);
        }
    }
}

// ---------------- k_gemm (MFMA bf16), body x3 DIAGNOSTIC ----------------
__global__ __launch_bounds__(256) void k_gemm(
    const float* __restrict__ X, const ushort_t* __restrict__ WT,
    float* __restrict__ HP)
{
    __shared__ ushort_t As[64 * 72];
    __shared__ ushort_t Bs[64 * 72];
    int t = threadIdx.x;
    int w = t >> 6;
    int lane = t & 63;
    int lr = lane & 15;
    int lk = lane >> 4;
    int r0 = blockIdx.y * 64;
    int c0 = blockIdx.x * 64;
    int kbase = blockIdx.z * (DIN / SPLITK);
    int srow = t >> 2, skq = (t & 3) * 16;

    for (int rep = 0; rep < 3; ++rep) {
        asm volatile("" ::: "memory");
        __syncthreads();

        f32x4 acc[4];
#pragma unroll
        for (int ct = 0; ct < 4; ++ct) acc[ct] = (f32x4){0.f, 0.f, 0.f, 0.f};

        for (int step = 0; step < 3; ++step) {
            int kk = kbase + step * 64;
            {
                const float4* xs = (const float4*)(X + (size_t)(r0 + srow) * DIN + kk + skq);
                float4 f0 = xs[0], f1 = xs[1], f2 = xs[2], f3 = xs[3];
                bf16x8 v0, v1;
                v0[0] = (__bf16)f0.x; v0[1] = (__bf16)f0.y; v0[2] = (__bf16)f0.z; v0[3] = (__bf16)f0.w;
                v0[4] = (__bf16)f1.x; v0[5] = (__bf16)f1.y; v0[6] = (__bf16)f1.z; v0[7] = (__bf16)f1.w;
                v1[0] = (__bf16)f2.x; v1[1] = (__bf16)f2.y; v1[2] = (__bf16)f2.z; v1[3] = (__bf16)f2.w;
                v1[4] = (__bf16)f3.x; v1[5] = (__bf16)f3.y; v1[6] = (__bf16)f3.z; v1[7] = (__bf16)f3.w;
                *(bf16x8*)&As[srow * 72 + skq] = v0;
                *(bf16x8*)&As[srow * 72 + skq + 8] = v1;
            }
            {
                const uint4* wp = (const uint4*)(WT + (size_t)(c0 + srow) * DIN + kk + skq);
                uint4 u0 = wp[0], u1 = wp[1];
                *(uint4*)&Bs[srow * 72 + skq] = u0;
                *(uint4*)&Bs[srow * 72 + skq + 8] = u1;
            }
            __syncthreads();
#pragma unroll
            for (int k2 = 0; k2 < 2; ++k2) {
                bf16x8 af = *(bf16x8*)&As[(w * 16 + lr) * 72 + k2 * 32 + lk * 8];
#pragma unroll
                for (int ct = 0; ct < 4; ++ct) {
                    bf16x8 bf_ = *(bf16x8*)&Bs[(ct * 16 + lr) * 72 + k2 * 32 + lk * 8];
                    acc[ct] = __builtin_amdgcn_mfma_f32_16x16x32_bf16(af, bf_, acc[ct], 0, 0, 0);
                }
            }
            __syncthreads();
        }
        float* outp = HP + (size_t)blockIdx.z * SL;
#pragma unroll
        for (int ct = 0; ct < 4; ++ct) {
            int col = c0 + ct * 16 + lr;
            if (col < DH) {
#pragma unroll
                for (int r = 0; r < 4; ++r) {
                    int row = r0 + w * 16 + lk * 4 + r;
                    outp[(size_t)row * DH + col] = acc[ct][r];
                }
            }
        }
    }
}

// ---------------- k_red, body x3 DIAGNOSTIC ----------------
__global__ __launch_bounds__(256) void k_red(
    const float* __restrict__ HP, const float* __restrict__ A,
    float* __restrict__ H, float* __restrict__ E2)
{
    int t = threadIdx.x;
    int row = blockIdx.x * 8 + (t >> 5);
    int lane = t & 31;
    const float4* a4 = (const float4*)(A + DH);
    float4* hout = (float4*)(H + (size_t)row * DH);
    for (int rep = 0; rep < 3; ++rep) {
        asm volatile("" ::: "memory");
        float acc = 0.f;
        for (int k4 = lane; k4 < DH / 4; k4 += 32) {
            float4 hv; hv.x = 0.f; hv.y = 0.f; hv.z = 0.f; hv.w = 0.f;
#pragma unroll
            for (int z = 0; z < SPLITK; ++z) {
                float4 v = ((const float4*)(HP + (size_t)z * SL + (size_t)row * DH))[k4];
                hv.x += v.x; hv.y += v.y; hv.z += v.z; hv.w += v.w;
            }
            float4 av = a4[k4];
            hout[k4] = hv;
            acc += hv.x * av.x + hv.y * av.y + hv.z * av.z + hv.w * av.w;
        }
#pragma unroll
        for (int o = 16; o >= 1; o >>= 1) acc += __shfl_xor(acc, o);
        if (lane == 0) E2[row] = acc;
    }
}

// ---------------- k_ef: R9 structure, single rep ----------------
__global__ __launch_bounds__(256) void k_ef(
    const float* __restrict__ EE, const float* __restrict__ CV,
    const float* __restrict__ C0, float* __restrict__ S)
{
    __shared__ __align__(16) float cl[DE];
    __shared__ float ps[3200];
    int bid = blockIdx.x;
    int t = threadIdx.x;
    if (t < DE) cl[t] = CV[t];
    const float c0v = C0[0];
    const f32x4* src = (const f32x4*)(EE + (size_t)bid * (L * DE));

    f32x4 v[13];
#pragma unroll
    for (int s = 0; s < 12; ++s) v[s] = src[t + 256 * s];
    if (t < 128) v[12] = src[t + 3072];
    else { v[12][0] = 0.f; v[12][1] = 0.f; v[12][2] = 0.f; v[12][3] = 0.f; }

    __syncthreads();

    int p = t % 25;
#pragma unroll
    for (int s = 0; s < 13; ++s) {
        int idx = t + 256 * s;
        if (s < 12 || t < 128) {
            const float4 c4 = *(const float4*)&cl[p * 4];
            ps[idx] = v[s][0] * c4.x + v[s][1] * c4.y + v[s][2] * c4.z + v[s][3] * c4.w;
        }
        p += 6; if (p >= 25) p -= 25;
    }
    __syncthreads();

    int r = t >> 1, h = t & 1;
    const float* pp = ps + 25 * r + h * 13;
    float s0 = 0.f;
#pragma unroll
    for (int m = 0; m < 12; ++m) s0 += pp[m];
    if (h == 0) s0 += pp[12];
    s0 += __shfl_xor(s0, 1);
    if (h == 0) S[(size_t)bid * L + r] = s0 + c0v;
}

// ---------------- k_sm_pv: single rep ----------------
__global__ __launch_bounds__(256) void k_sm_pv(
    const float* __restrict__ S, const int* __restrict__ ADJ,
    const float* __restrict__ H, const float* __restrict__ E2,
    const float* __restrict__ VW, const int* __restrict__ VCOL,
    float* __restrict__ OUT)
{
    __shared__ float hrow[IG][DH];
    __shared__ float att[IG][L];
    int blk = blockIdx.x;
    int b = blk >> 6;
    int i0 = (blk & 63) * IG;
    int bid0 = b * L + i0;
    int t = threadIdx.x;

    for (int idx = t; idx < IG * DH; idx += 256) {
        int r = idx / DH, k = idx - r * DH;
        hrow[r][k] = H[(size_t)(bid0 + r) * DH + k];
    }
    __syncthreads();

    {
        int r = t >> 7, j = t & 127;
        int bid = bid0 + r;
        float s = S[(size_t)bid * L + j];
        float ewv = 1.f / (1.f + expf(-s));
        int cm = VCOL[j];
        float e1 = 0.f;
#pragma unroll
        for (int u = 0; u < 4; ++u) {
            int c = cm + u; if (c > DH - 1) c = DH - 1;
            e1 += VW[j * 4 + u] * hrow[r][c];
        }
        float e = e1 + E2[(size_t)b * L + j];
        e = (e > 0.f) ? e : 0.2f * e;
        att[r][j] = (ADJ[(size_t)bid * L + j] > 0) ? e * ewv : -9.0e15f;
    }
    __syncthreads();

    {
        int w = t >> 6, lane = t & 63;
        if (w < IG) {
            float v0 = att[w][lane], v1 = att[w][lane + 64];
            float m = fmaxf(v0, v1);
#pragma unroll
            for (int o = 32; o >= 1; o >>= 1) m = fmaxf(m, __shfl_xor(m, o));
            float p0 = expf(v0 - m), p1 = expf(v1 - m);
            float sm = p0 + p1;
#pragma unroll
            for (int o = 32; o >= 1; o >>= 1) sm += __shfl_xor(sm, o);
            float inv = 1.f / sm;
            att[w][lane] = p0 * inv;
            att[w][lane + 64] = p1 * inv;
        }
    }
    __syncthreads();

    const float* Hb = H + (size_t)b * L * DH;
    for (int k = t; k < DH; k += 256) {
        float a0 = hrow[0][k], c0a = 0.f;
        float a1 = hrow[1][k], c1a = 0.f;
#pragma unroll 2
        for (int j = 0; j < L; j += 4) {
            float h0 = Hb[(size_t)(j + 0) * DH + k];
            float h1 = Hb[(size_t)(j + 1) * DH + k];
            float h2 = Hb[(size_t)(j + 2) * DH + k];
            float h3 = Hb[(size_t)(j + 3) * DH + k];
            a0  = fmaf(att[0][j + 0], h0, a0);
            c0a = fmaf(att[0][j + 1], h1, c0a);
            a0  = fmaf(att[0][j + 2], h2, a0);
            c0a = fmaf(att[0][j + 3], h3, c0a);
            a1  = fmaf(att[1][j + 0], h0, a1);
            c1a = fmaf(att[1][j + 1], h1, c1a);
            a1  = fmaf(att[1][j + 2], h2, a1);
            c1a = fmaf(att[1][j + 3], h3, c1a);
        }
        OUT[(size_t)(bid0 + 0) * DH + k] = a0 + c0a;
        OUT[(size_t)(bid0 + 1) * DH + k] = a1 + c1a;
    }
}

extern "C" void kernel_launch(void* const* d_in, const int* in_sizes, int n_in,
                              void* d_out, int out_size, void* d_ws, size_t ws_size,
                              hipStream_t stream) {
    const float* X   = (const float*)d_in[0];
    const int*   ADJ = (const int*)d_in[1];
    const float* EE  = (const float*)d_in[2];
    const float* Wm  = (const float*)d_in[3];
    const float* A   = (const float*)d_in[4];
    const float* EMW = (const float*)d_in[5];
    const float* EMB = (const float*)d_in[6];
    const float* ELW = (const float*)d_in[7];
    const float* ELB = (const float*)d_in[8];
    float* OUT = (float*)d_out;

    float* ws = (float*)d_ws;
    float* HP   = ws;                    // 4 * 614400 = 2457600
    float* H    = ws + 2457600;          // 614400
    float* E2   = ws + 3072000;          // 2048
    float* CV   = ws + 3074048;          // 100
    float* C0   = ws + 3074148;          // 4 (pad)
    float* VW   = ws + 3074152;          // 512
    int*   VCOL = (int*)(ws + 3074664);  // 128 (+pad 24)
    ushort_t* WT = (ushort_t*)(ws + 3074816); // 320*768 bf16
    float* Sbuf = ws + 3197696;          // 2048*128

    k_pre<<<dim3(62), dim3(256), 0, stream>>>(A, EMW, EMB, ELW, ELB, Wm, CV, C0, VW, VCOL, WT);
    k_gemm<<<dim3(5, 32, SPLITK), dim3(256), 0, stream>>>(X, WT, HP);
    k_red<<<dim3(256), dim3(256), 0, stream>>>(HP, A, H, E2);
    k_ef<<<dim3(2048), dim3(256), 0, stream>>>(EE, CV, C0, Sbuf);
    k_sm_pv<<<dim3(1024), dim3(256), 0, stream>>>(Sbuf, ADJ, H, E2, VW, VCOL, OUT);
}

// Round 14
// 72.172 us; speedup vs baseline: 1.4951x; 1.1045x over previous
//
#include <hip/hip_runtime.h>
#include <hip/hip_bf16.h>

// Problem: GraphAttentionLayer  B=16, L=128, DIN=768, DH=300, DE=100
// Device dtypes: all float tensors fp32, adj int32, out fp32.
//
// R13->R14: per-kernel repeat-diagnostics bounded ALL kernels: ef~10, smpv~3,
// gemm~2.5, red~1.5, pre~3 (warm) => ~20us work in a ~72us wall. Residual
// ~50us = per-dispatch fixed cost (launch+drain+cold) x 6 kernels.
// Fix: 6 -> 3 dispatches. k_gemm drops split-K (no HP/k_red), converts W
// inline (no WT), fuses e2 via shfl+atomicAdd. k_attn refuses ef+sm+pv.

#define L 128
#define DH 300
#define DIN 768
#define DE 100
#define MROWS 2048

typedef __bf16 bf16x8 __attribute__((ext_vector_type(8)));
typedef float f32x4 __attribute__((ext_vector_type(4)));
typedef unsigned short ushort_t;

// ---------------- k_pre: CV, C0, band-V, E2 zero ----------------
__global__ __launch_bounds__(256) void k_pre(
    const float* __restrict__ A, const float* __restrict__ EMW,
    const float* __restrict__ EMB, const float* __restrict__ ELW,
    const float* __restrict__ ELB,
    float* __restrict__ CV, float* __restrict__ C0,
    float* __restrict__ VW, int* __restrict__ VCOL,
    float* __restrict__ E2)
{
    __shared__ float Als[304];
    int t = threadIdx.x;
    if (blockIdx.x == 0) {
        // CV: 2 threads per d, k split 150/150
        float part = 0.f;
        int d = t >> 1, g = t & 1;
        if (d < DE) {
            int k0 = g * 150;
            for (int k = k0; k < k0 + 150; ++k)
                part = fmaf(ELW[k], EMW[k * DE + d], part);
        }
        part += __shfl_xor(part, 1);
        if (d < DE && g == 0) CV[d] = part;
        // C0: wave 0
        if (t < 64) {
            float s = 0.f;
            for (int k = t; k < DH; k += 64) s = fmaf(ELW[k], EMB[k], s);
#pragma unroll
            for (int o = 32; o >= 1; o >>= 1) s += __shfl_xor(s, o);
            if (t == 0) C0[0] = s + ELB[0];
        }
    } else {
        // zero E2 (atomic target)
        for (int idx = t; idx < MROWS; idx += 256) E2[idx] = 0.f;
        for (int idx = t; idx < DH; idx += 256) Als[idx] = A[idx];
        __syncthreads();
        if (t < L) {
            int base = t * DH;
            int cm = base >> 7;
            float w[4];
#pragma unroll
            for (int u = 0; u < 4; ++u) {
                int js = 128 * (cm + u) - base;
                int je = js + 128;
                if (js < 0) js = 0;
                if (je > DH) je = DH;
                float s = 0.f;
                for (int j = js; j < je; ++j) s += Als[j];
                w[u] = (je > js) ? s : 0.f;
            }
            VCOL[t] = cm;
            VW[t * 4 + 0] = w[0]; VW[t * 4 + 1] = w[1];
            VW[t * 4 + 2] = w[2]; VW[t * 4 + 3] = w[3];
        }
    }
}

// ---------------- k_gemm: h = x @ W (MFMA bf16, full K, fused e2) ----------------
// grid (5 colTiles, 32 rowTiles) = 160 blocks, 256 threads (4 waves)
// tile 64x64, K-step 64, 12 steps. W converted fp32->bf16 inline (LDS transpose).
// Epilogue: H store + e2 row-partials via shfl + atomicAdd.
__global__ __launch_bounds__(256) void k_gemm(
    const float* __restrict__ X,     // (2048, 768)
    const float* __restrict__ Wm,    // (768, 300)
    const float* __restrict__ A,     // a (600,); a2 = A+300
    float* __restrict__ H, float* __restrict__ E2)
{
    __shared__ ushort_t As[64 * 72];   // [row][k]
    __shared__ ushort_t Bs[64 * 72];   // [col][k]
    int t = threadIdx.x;
    int w = t >> 6;
    int lane = t & 63;
    int lr = lane & 15;
    int lk = lane >> 4;
    int r0 = blockIdx.y * 64;
    int c0 = blockIdx.x * 64;

    f32x4 acc[4];
#pragma unroll
    for (int ct = 0; ct < 4; ++ct) acc[ct] = (f32x4){0.f, 0.f, 0.f, 0.f};

    int srow = t >> 2, skq = (t & 3) * 16;   // A staging role
    int bc4 = t & 15, bkr = t >> 4;          // B staging role

    for (int step = 0; step < 12; ++step) {
        int kk = step * 64;
        // stage A: X fp32 -> bf16, [row][k]
        {
            const float4* xs = (const float4*)(X + (size_t)(r0 + srow) * DIN + kk + skq);
            float4 f0 = xs[0], f1 = xs[1], f2 = xs[2], f3 = xs[3];
            bf16x8 v0, v1;
            v0[0] = (__bf16)f0.x; v0[1] = (__bf16)f0.y; v0[2] = (__bf16)f0.z; v0[3] = (__bf16)f0.w;
            v0[4] = (__bf16)f1.x; v0[5] = (__bf16)f1.y; v0[6] = (__bf16)f1.z; v0[7] = (__bf16)f1.w;
            v1[0] = (__bf16)f2.x; v1[1] = (__bf16)f2.y; v1[2] = (__bf16)f2.z; v1[3] = (__bf16)f2.w;
            v1[4] = (__bf16)f3.x; v1[5] = (__bf16)f3.y; v1[6] = (__bf16)f3.z; v1[7] = (__bf16)f3.w;
            *(bf16x8*)&As[srow * 72 + skq] = v0;
            *(bf16x8*)&As[srow * 72 + skq + 8] = v1;
        }
        // stage B: W[k][c] fp32 -> bf16 transposed to [col][k]
#pragma unroll
        for (int p = 0; p < 4; ++p) {
            int krow = bkr + p * 16;
            int col = c0 + bc4 * 4;
            float4 v;
            if (col + 3 < DH) v = *(const float4*)(Wm + (size_t)(kk + krow) * DH + col);
            else { v.x = 0.f; v.y = 0.f; v.z = 0.f; v.w = 0.f; }
            Bs[(bc4 * 4 + 0) * 72 + krow] = (ushort_t)__builtin_bit_cast(unsigned short, (__bf16)v.x);
            Bs[(bc4 * 4 + 1) * 72 + krow] = (ushort_t)__builtin_bit_cast(unsigned short, (__bf16)v.y);
            Bs[(bc4 * 4 + 2) * 72 + krow] = (ushort_t)__builtin_bit_cast(unsigned short, (__bf16)v.z);
            Bs[(bc4 * 4 + 3) * 72 + krow] = (ushort_t)__builtin_bit_cast(unsigned short, (__bf16)v.w);
        }
        __syncthreads();
#pragma unroll
        for (int k2 = 0; k2 < 2; ++k2) {
            bf16x8 af = *(bf16x8*)&As[(w * 16 + lr) * 72 + k2 * 32 + lk * 8];
#pragma unroll
            for (int ct = 0; ct < 4; ++ct) {
                bf16x8 bf_ = *(bf16x8*)&Bs[(ct * 16 + lr) * 72 + k2 * 32 + lk * 8];
                acc[ct] = __builtin_amdgcn_mfma_f32_16x16x32_bf16(af, bf_, acc[ct], 0, 0, 0);
            }
        }
        __syncthreads();
    }
    // epilogue: store H, fuse e2 = h . a2
    float a2v[4];
#pragma unroll
    for (int ct = 0; ct < 4; ++ct) {
        int col = ct * 16 + lr;                  // local col
        a2v[ct] = (c0 + col < DH) ? A[DH + c0 + col] : 0.f;
    }
#pragma unroll
    for (int r = 0; r < 4; ++r) {
        int row = r0 + w * 16 + lk * 4 + r;
        float e2p = 0.f;
#pragma unroll
        for (int ct = 0; ct < 4; ++ct) {
            int col = c0 + ct * 16 + lr;
            if (col < DH) H[(size_t)row * DH + col] = acc[ct][r];
            e2p = fmaf(acc[ct][r], a2v[ct], e2p);
        }
        // reduce over the 16 lanes (lr) sharing this row
        e2p += __shfl_xor(e2p, 1);
        e2p += __shfl_xor(e2p, 2);
        e2p += __shfl_xor(e2p, 4);
        e2p += __shfl_xor(e2p, 8);
        if (lr == 0) atomicAdd(&E2[row], e2p);
    }
}

// ---------------- k_attn: fused ef + softmax + PV, one block per (b,i) ----------------
__global__ __launch_bounds__(256) void k_attn(
    const float* __restrict__ EE,  // (B,L,L,DE) fp32
    const int* __restrict__ ADJ,   // (B,L,L) int32
    const float* __restrict__ H,   // (2048, 300)
    const float* __restrict__ E2,  // (2048,)
    const float* __restrict__ CV, const float* __restrict__ C0,
    const float* __restrict__ VW, const int* __restrict__ VCOL,
    float* __restrict__ OUT)
{
    __shared__ __align__(16) float cl[DE];
    __shared__ float ps[3200];
    __shared__ float hrow[DH];
    __shared__ float ef[L];
    __shared__ float att[L];
    __shared__ float red[4];

    int bid = blockIdx.x;
    int b = bid >> 7;
    int t = threadIdx.x;
    const f32x4* src = (const f32x4*)(EE + (size_t)bid * (L * DE));

    // 13-deep register batch of EE loads (one exposed latency)
    f32x4 v[13];
#pragma unroll
    for (int s = 0; s < 12; ++s) v[s] = src[t + 256 * s];
    if (t < 128) v[12] = src[t + 3072];
    else { v[12][0] = 0.f; v[12][1] = 0.f; v[12][2] = 0.f; v[12][3] = 0.f; }

    for (int k = t; k < DH; k += 256) hrow[k] = H[(size_t)bid * DH + k];
    if (t < DE) cl[t] = CV[t];
    __syncthreads();

    // partial dot per float4 (row = idx/25, p = idx%25 tracked incrementally)
    int p = t % 25;
#pragma unroll
    for (int s = 0; s < 13; ++s) {
        int idx = t + 256 * s;
        if (s < 12 || t < 128) {
            const float4 c4 = *(const float4*)&cl[p * 4];
            ps[idx] = v[s][0] * c4.x + v[s][1] * c4.y + v[s][2] * c4.z + v[s][3] * c4.w;
        }
        p += 6; if (p >= 25) p -= 25;
    }
    __syncthreads();

    // 2 threads per row: reduce 25 partials, then full e_final inline
    {
        int r = t >> 1, h = t & 1;
        const float* pp = ps + 25 * r + h * 13;
        float s0 = 0.f;
#pragma unroll
        for (int m = 0; m < 12; ++m) s0 += pp[m];
        if (h == 0) s0 += pp[12];
        s0 += __shfl_xor(s0, 1);
        if (h == 0) {
            float sv = s0 + C0[0];
            float ewv = 1.f / (1.f + expf(-sv));
            int cm = VCOL[r];
            float e1 = 0.f;
#pragma unroll
            for (int u = 0; u < 4; ++u) {
                int c = cm + u; if (c > DH - 1) c = DH - 1;
                e1 += VW[r * 4 + u] * hrow[c];
            }
            float e = e1 + E2[(size_t)b * L + r];
            e = (e > 0.f) ? e : 0.2f * e;
            ef[r] = (ADJ[(size_t)bid * L + r] > 0) ? e * ewv : -9.0e15f;
        }
    }
    __syncthreads();

    // softmax over 128
    float vv = (t < L) ? ef[t] : -3.0e38f;
#pragma unroll
    for (int o = 32; o >= 1; o >>= 1) vv = fmaxf(vv, __shfl_xor(vv, o));
    int wid = t >> 6;
    if ((t & 63) == 0) red[wid] = vv;
    __syncthreads();
    float mx = fmaxf(fmaxf(red[0], red[1]), fmaxf(red[2], red[3]));
    __syncthreads();
    float pe = (t < L) ? expf(ef[t] - mx) : 0.f;
    vv = pe;
#pragma unroll
    for (int o = 32; o >= 1; o >>= 1) vv += __shfl_xor(vv, o);
    if ((t & 63) == 0) red[wid] = vv;
    __syncthreads();
    float denom = red[0] + red[1] + red[2] + red[3];
    if (t < L) att[t] = pe / denom;
    __syncthreads();

    // PV: out = h_row + att @ h[b]
    const float* Hb = H + (size_t)b * L * DH;
    for (int k = t; k < DH; k += 256) {
        float a0 = hrow[k], a1 = 0.f, a2 = 0.f, a3 = 0.f;
#pragma unroll 4
        for (int j = 0; j < L; j += 4) {
            a0 = fmaf(att[j + 0], Hb[(size_t)(j + 0) * DH + k], a0);
            a1 = fmaf(att[j + 1], Hb[(size_t)(j + 1) * DH + k], a1);
            a2 = fmaf(att[j + 2], Hb[(size_t)(j + 2) * DH + k], a2);
            a3 = fmaf(att[j + 3], Hb[(size_t)(j + 3) * DH + k], a3);
        }
        OUT[(size_t)bid * DH + k] = (a0 + a1) + (a2 + a3);
    }
}

extern "C" void kernel_launch(void* const* d_in, const int* in_sizes, int n_in,
                              void* d_out, int out_size, void* d_ws, size_t ws_size,
                              hipStream_t stream) {
    const float* X   = (const float*)d_in[0];
    const int*   ADJ = (const int*)d_in[1];
    const float* EE  = (const float*)d_in[2];
    const float* Wm  = (const float*)d_in[3];
    const float* A   = (const float*)d_in[4];
    const float* EMW = (const float*)d_in[5];
    const float* EMB = (const float*)d_in[6];
    const float* ELW = (const float*)d_in[7];
    const float* ELB = (const float*)d_in[8];
    float* OUT = (float*)d_out;

    float* ws = (float*)d_ws;
    float* H    = ws;                    // 614400
    float* E2   = ws + 614400;           // 2048
    float* CV   = ws + 616448;           // 100
    float* C0   = ws + 616548;           // 4 (pad)
    float* VW   = ws + 616552;           // 512
    int*   VCOL = (int*)(ws + 617064);   // 128

    k_pre<<<dim3(2), dim3(256), 0, stream>>>(A, EMW, EMB, ELW, ELB, CV, C0, VW, VCOL, E2);
    k_gemm<<<dim3(5, 32), dim3(256), 0, stream>>>(X, Wm, A, H, E2);
    k_attn<<<dim3(2048), dim3(256), 0, stream>>>(EE, ADJ, H, E2, CV, C0, VW, VCOL, OUT);
}